// Round 8
// baseline (202.689 us; speedup 1.0000x reference)
//
#include <hip/hip_runtime.h>
#include <math.h>

#define CSTRIDE (512 * 512)

// numpy generic-strided einsum inner loop (scalar C, no SIMD, no FMA):
// accum += c[q]*v[q], q ascending, 64-deep sequential chain, each term
// mul-rounded then add-rounded.
__device__ __forceinline__ float chain_dot64_nofma(const float* __restrict__ c,
                                                   const float* __restrict__ v)
{
#pragma clang fp contract(off)
    float s = 0.0f;
#pragma unroll
    for (int q = 0; q < 64; ++q) s = s + c[q] * v[q];
    return s;
}

__global__ __launch_bounds__(256, 2)
void jpeg_kernel(const float* __restrict__ img,
                 const float* __restrict__ rgb2yuv,
                 const float* __restrict__ yuv2rgb,
                 const float* __restrict__ dctC,
                 const float* __restrict__ qlum,
                 const float* __restrict__ qchrom,
                 float* __restrict__ out)
{
#pragma clang fp contract(off)
    __shared__ float V[3][4096];   // 48 KB: per-channel (q=x*8+y)[64] x block[64]
    __shared__ float Fb[4096];     // 16 KB: output restage (row-major 8x512)

    const int tid  = threadIdx.x;
    const int lane = tid & 63;                                        // block index
    const int p0u  = __builtin_amdgcn_readfirstlane((tid >> 6) * 16); // wave's p range

    const int b  = blockIdx.x >> 6;
    const int y0 = (blockIdx.x & 63) << 3;
    const size_t base0 = (size_t)b * 3 * CSTRIDE + (size_t)y0 * 512;

    const float r00 = rgb2yuv[0], r01 = rgb2yuv[1], r02 = rgb2yuv[2];
    const float r10 = rgb2yuv[3], r11 = rgb2yuv[4], r12 = rgb2yuv[5];
    const float r20 = rgb2yuv[6], r21 = rgb2yuv[7], r22 = rgb2yuv[8];

    // Phase 1: coalesced RGB loads; numpy color loop model (no FMA):
    // out = fl(fl(fl(m0*r) + fl(m1*g)) + fl(m2*b)); then fl(fl(yuv*255)-128)
#pragma unroll
    for (int i = 0; i < 4; ++i) {
        const size_t f4 = 4 * (size_t)(tid + 256 * i);
        const float4 R4 = *(const float4*)(img + base0 + f4);
        const float4 G4 = *(const float4*)(img + base0 + CSTRIDE + f4);
        const float4 B4 = *(const float4*)(img + base0 + 2 * CSTRIDE + f4);
        const float* rp = (const float*)&R4;
        const float* gp = (const float*)&G4;
        const float* bp = (const float*)&B4;
#pragma unroll
        for (int jj = 0; jj < 4; ++jj) {
            const int flat = 4 * (tid + 256 * i) + jj;   // x*512 + col
            const int w = flat & 511, x = flat >> 9;
            const int idx = ((x << 3) + (w & 7)) * 64 + (w >> 3);
            const float r_ = rp[jj], g_ = gp[jj], b_ = bp[jj];
            float t;
            t = (r00 * r_ + r01 * g_) + r02 * b_;  V[0][idx] = t * 255.0f - 128.0f;
            t = (r10 * r_ + r11 * g_) + r12 * b_;  V[1][idx] = t * 255.0f - 128.0f;
            t = (r20 * r_ + r21 * g_) + r22 * b_;  V[2][idx] = t * 255.0f - 128.0f;
        }
    }
    __syncthreads();

    for (int c = 0; c < 3; ++c) {
        float* Vc = V[c];

        // preload this thread's block column (64 VGPRs)
        float v[64];
#pragma unroll
        for (int q = 0; q < 64; ++q) v[q] = Vc[q * 64 + lane];
        __syncthreads();   // all waves preloaded before we overwrite V[c]

        // forward DCT: 64-deep sequential mul+add chain, then quantize/dequant
        const float* qtab = (c == 0) ? qlum : qchrom;
        for (int j = 0; j < 16; ++j) {
            const float* Crow = dctC + (size_t)(p0u + j) * 64;  // uniform -> s_load
            const float d  = chain_dot64_nofma(Crow, v);
            const float qv = qtab[p0u + j];
            const float dq = rintf(d / qv) * qv;   // fp32 div, half-even, fp32 mul
            Vc[(p0u + j) * 64 + lane] = dq;
        }
        __syncthreads();

        // preload quantized coefficients
        float v2[64];
#pragma unroll
        for (int q = 0; q < 64; ++q) v2[q] = Vc[q * 64 + lane];
        __syncthreads();

        // inverse: same flat matrix, same sequential chain
        for (int j = 0; j < 16; ++j) {
            const float* Crow = dctC + (size_t)(p0u + j) * 64;
            Vc[(p0u + j) * 64 + lane] = chain_dot64_nofma(Crow, v2);
        }
        // writes re-read only by the owning thread -> no barrier needed here
    }
    __syncthreads();

    // Output: fl(fl(x+128)/255), no-FMA sequential color chain, coalesced stores
    for (int oc = 0; oc < 3; ++oc) {
        const float m0 = yuv2rgb[3 * oc + 0];
        const float m1 = yuv2rgb[3 * oc + 1];
        const float m2 = yuv2rgb[3 * oc + 2];
        for (int j = 0; j < 16; ++j) {
            const int p = p0u + j;           // spatial: x = p>>3, y = p&7
            const int cell = p * 64 + lane;
            const float Yv = (V[0][cell] + 128.0f) / 255.0f;
            const float Uv = (V[1][cell] + 128.0f) / 255.0f;
            const float Wv = (V[2][cell] + 128.0f) / 255.0f;
            Fb[(p >> 3) * 512 + 8 * lane + (p & 7)] = (m0 * Yv + m1 * Uv) + m2 * Wv;
        }
        __syncthreads();
#pragma unroll
        for (int i = 0; i < 4; ++i) {
            const size_t f4 = 4 * (size_t)(tid + 256 * i);
            *(float4*)(out + base0 + (size_t)oc * CSTRIDE + f4) = *(const float4*)(Fb + f4);
        }
        __syncthreads();   // Fb reused by next oc
    }
}

extern "C" void kernel_launch(void* const* d_in, const int* in_sizes, int n_in,
                              void* d_out, int out_size, void* d_ws, size_t ws_size,
                              hipStream_t stream) {
    const float* img = (const float*)d_in[0];
    const float* r2y = (const float*)d_in[1];
    const float* y2r = (const float*)d_in[2];
    const float* C   = (const float*)d_in[3];
    const float* ql  = (const float*)d_in[4];
    const float* qc  = (const float*)d_in[5];
    float* o = (float*)d_out;

    jpeg_kernel<<<dim3(16 * 64), dim3(256), 0, stream>>>(img, r2y, y2r, C, ql, qc, o);
}